// Round 17
// baseline (94.541 us; speedup 1.0000x reference)
//
#include <hip/hip_runtime.h>
#include <stdint.h>

#define N_ROWS 4096
#define D_DIM  1024
#define ROWB   1024   // bytes per row in i8
#define T_TEMP 0.15f

#define AS1 __attribute__((address_space(1)))
#define AS3 __attribute__((address_space(3)))

typedef int i32x4v __attribute__((ext_vector_type(4)));
typedef int i32x16 __attribute__((ext_vector_type(16)));

__device__ __forceinline__ float wsum(float v) {
#pragma unroll
  for (int m = 32; m >= 1; m >>= 1) v += __shfl_xor(v, m, 64);
  return v;
}
__device__ __forceinline__ float wmax(float v) {
#pragma unroll
  for (int m = 32; m >= 1; m >>= 1) v = fmaxf(v, __shfl_xor(v, m, 64));
  return v;
}

// One WAVE per row (no barriers): norms, x.y dot (-> log pos), softmax-JS
// per-row term -> js[row]. Per-row symmetric i8 quantization (scale
// cancels in cosine): q = rint(x * 127/rowmax|x|), natural row-major
// layout in Bb = [x;y]; inv_n = 1/|q|. Zeroes rowsum. (R15-verified.)
__global__ __launch_bounds__(256) void prep_kernel(
    const float* __restrict__ x, const float* __restrict__ y,
    unsigned char* __restrict__ Bb, float* __restrict__ inv_n,
    float* __restrict__ logpos, float* __restrict__ js,
    float* __restrict__ rowsum) {
  if (threadIdx.x < 4) rowsum[blockIdx.x * 4 + threadIdx.x] = 0.0f;

  const int wid = threadIdx.x >> 6, lane = threadIdx.x & 63;
  const int row = blockIdx.x * 4 + wid;
  const float4* xp = (const float4*)(x + (size_t)row * D_DIM) + lane * 4;
  const float4* yp = (const float4*)(y + (size_t)row * D_DIM) + lane * 4;

  float xv[16], yv[16];
#pragma unroll
  for (int i = 0; i < 4; ++i) {
    float4 a = xp[i], b = yp[i];
    xv[i*4+0]=a.x; xv[i*4+1]=a.y; xv[i*4+2]=a.z; xv[i*4+3]=a.w;
    yv[i*4+0]=b.x; yv[i*4+1]=b.y; yv[i*4+2]=b.z; yv[i*4+3]=b.w;
  }

  float sx2=0.f, sy2=0.f, sxy=0.f, mx=-1e30f, my=-1e30f, ax=0.f, ay=0.f;
#pragma unroll
  for (int k = 0; k < 16; ++k) {
    sx2 = fmaf(xv[k], xv[k], sx2);
    sy2 = fmaf(yv[k], yv[k], sy2);
    sxy = fmaf(xv[k], yv[k], sxy);
    mx = fmaxf(mx, xv[k]); my = fmaxf(my, yv[k]);
    ax = fmaxf(ax, fabsf(xv[k])); ay = fmaxf(ay, fabsf(yv[k]));
  }
  sx2 = wsum(sx2); sy2 = wsum(sy2); sxy = wsum(sxy);
  mx = wmax(mx);  my = wmax(my);
  ax = wmax(ax);  ay = wmax(ay);

  float ex[16], ey[16], sex=0.f, sey=0.f;
#pragma unroll
  for (int k = 0; k < 16; ++k) {
    ex[k] = __expf(xv[k] - mx); ey[k] = __expf(yv[k] - my);
    sex += ex[k]; sey += ey[k];
  }
  sex = wsum(sex); sey = wsum(sey);
  const float lsex = __logf(sex), lsey = __logf(sey);
  const float rsex = 1.f / sex,  rsey = 1.f / sey;

  float term = 0.f;
#pragma unroll
  for (int k = 0; k < 16; ++k) {
    float a = ex[k] * rsex, b = ey[k] * rsey;
    float lm = __logf(0.5f * (a + b));
    term += a * ((xv[k] - mx - lsex) - lm) + b * ((yv[k] - my - lsey) - lm);
  }
  term = wsum(term);

  // quantize: q = rint(x * 127/rowmax); accumulate |q|^2
  const float sxq = 127.0f / ax, syq = 127.0f / ay;
  int qx[16], qy[16];
  float q2x = 0.f, q2y = 0.f;
#pragma unroll
  for (int k = 0; k < 16; ++k) {
    qx[k] = (int)rintf(xv[k] * sxq);
    qy[k] = (int)rintf(yv[k] * syq);
    q2x += (float)(qx[k] * qx[k]);
    q2y += (float)(qy[k] * qy[k]);
  }
  q2x = wsum(q2x); q2y = wsum(q2y);

  if (lane == 0) {
    const float nx = sqrtf(sx2), ny = sqrtf(sy2);
    inv_n[row] = rsqrtf(q2x);            // 1/|q_x|
    inv_n[N_ROWS + row] = rsqrtf(q2y);   // 1/|q_y|
    logpos[row] = sxy / fmaxf(nx * ny, 1e-8f) / T_TEMP;  // ln(pos), exact fp32
    js[row] = term;
  }

  int p[4], q[4];
#pragma unroll
  for (int w = 0; w < 4; ++w) {
    p[w] = (qx[4*w] & 255) | ((qx[4*w+1] & 255) << 8) |
           ((qx[4*w+2] & 255) << 16) | ((qx[4*w+3] & 255) << 24);
    q[w] = (qy[4*w] & 255) | ((qy[4*w+1] & 255) << 8) |
           ((qy[4*w+2] & 255) << 16) | ((qy[4*w+3] & 255) << 24);
  }
  *(int4*)(Bb + (size_t)row * ROWB + lane * 16) = make_int4(p[0], p[1], p[2], p[3]);
  *(int4*)(Bb + (size_t)(N_ROWS + row) * ROWB + lane * 16) = make_int4(q[0], q[1], q[2], q[3]);
}

// ===== i8 symmetric fused GEMM, 128x128, 4 waves, BK=64, raw 2-phase =====
// R15's winning schedule byte-for-byte; compute switched to
// mfma_i32_32x32x32_i8 (4404 TOPS, 8 MFMA/tile instead of 16). Per-wave
// C = 64x64 = 2x2 tiles of 32x32. Operand: lane (l31,l5) holds row/col
// base+l31, k-unit l5 of each k-step (16B) -- read from the SAME swizzled
// LDS (slot = unit ^ ((row>>1)&3)); 8-lane phases hit 8 distinct bank
// quads (enumerated). C/D mapping col=l31,row=(r&3)+8(r>>2)+4*l5
// (verified R5/R6, absmax 0).
#define GLL(src, dst) __builtin_amdgcn_global_load_lds((const AS1 void*)(src), (AS3 void*)(dst), 16, 0, 0)
#define SBAR __builtin_amdgcn_sched_barrier(0)

__global__ __launch_bounds__(256, 3) void gemm_fused(
    const unsigned char* __restrict__ Bb, const float* __restrict__ inv_n,
    float* __restrict__ rowsum) {
  __shared__ __align__(16) char As[2 * 8192];   // [buf][128][64]
  __shared__ __align__(16) char Bs[2 * 8192];
  const int tid = threadIdx.x;
  const int wid = tid >> 6, lane = tid & 63;
  const int l31 = lane & 31, l5 = lane >> 5;

  int bi, bj;
  bool sym = false;
  {
    const int idx = blockIdx.x;
    if (idx < 1024) {
      bi = idx >> 5; bj = 32 + (idx & 31);
    } else {
      const int t = idx - 1024;
      int b = (int)((65.0 - sqrt((double)(4225 - 8 * t))) * 0.5);
      while ((b + 1) * (65 - (b + 1)) / 2 <= t) ++b;
      while (b * (65 - b) / 2 > t) --b;
      bi = b;
      bj = b + (t - b * (65 - b) / 2);
      sym = (bi != bj);
    }
  }
  const int grow0 = bi * 128;
  const int gcol0 = bj * 128;
  const int wrow = (wid >> 1) * 64, wcol = (wid & 1) * 64;

  i32x16 acc[2][2] = {};

  // staging (R15-identical): thread t -> row t>>2 (per 64-row half),
  // slot t&3; source 16B unit pre-swizzled h = (t&3) ^ ((t>>3)&3).
  const int sr = tid >> 2;
  const int sh = (tid & 3) ^ ((tid >> 3) & 3);
  const char* gA = (const char*)Bb + (size_t)(grow0 + sr) * ROWB + sh * 16;
  const char* gB = (const char*)Bb + (size_t)(gcol0 + sr) * ROWB + sh * 16;

#define STG(kt_, b_) do { \
    GLL(gA + (size_t)(kt_) * 64,                      As + (b_) * 8192 + tid * 16); \
    GLL(gA + 64 * (size_t)ROWB + (size_t)(kt_) * 64,  As + (b_) * 8192 + 4096 + tid * 16); \
    GLL(gB + (size_t)(kt_) * 64,                      Bs + (b_) * 8192 + tid * 16); \
    GLL(gB + 64 * (size_t)ROWB + (size_t)(kt_) * 64,  Bs + (b_) * 8192 + 4096 + tid * 16); \
  } while (0)

  // fragment read: row = base + l31 (base mult of 32 -> xr = (l31>>1)&3),
  // unit u = s*2 + l5, slot = u ^ xr.
  const int xr = (l31 >> 1) & 3;
  const int sl0 = ((l5) ^ xr) * 16;        // s=0: u = l5
  const int sl1 = ((2 + l5) ^ xr) * 16;    // s=1: u = 2 + l5

  i32x4v a[2][2], bv[2][2];   // [s][tile]

#define RD_FRAGS(b_) do { _Pragma("unroll") \
    for (int mt_ = 0; mt_ < 2; ++mt_) { \
      const char* ra = As + (b_) * 8192 + (wrow + mt_ * 32 + l31) * 64; \
      a[0][mt_] = *(const i32x4v*)(ra + sl0); \
      a[1][mt_] = *(const i32x4v*)(ra + sl1); \
      const char* rb = Bs + (b_) * 8192 + (wcol + mt_ * 32 + l31) * 64; \
      bv[0][mt_] = *(const i32x4v*)(rb + sl0); \
      bv[1][mt_] = *(const i32x4v*)(rb + sl1); \
    } \
  } while (0)

#define MFMA8 do { _Pragma("unroll") \
    for (int s_ = 0; s_ < 2; ++s_) \
      _Pragma("unroll") \
      for (int nt_ = 0; nt_ < 2; ++nt_) \
        _Pragma("unroll") \
        for (int mt_ = 0; mt_ < 2; ++mt_) \
          acc[mt_][nt_] = __builtin_amdgcn_mfma_i32_32x32x32_i8( \
              a[s_][mt_], bv[s_][nt_], acc[mt_][nt_], 0, 0, 0); \
  } while (0)

  // prologue: stage tile 0 into buf 0, publish
  STG(0, 0);
  asm volatile("s_waitcnt vmcnt(0)" ::: "memory");
  __builtin_amdgcn_s_barrier();

#pragma unroll 1
  for (int kt = 0; kt < 15; ++kt) {
    const int b = kt & 1;
    RD_FRAGS(b);                 // 8 ds_read_b128 from buf b
    SBAR;
    STG(kt + 1, b ^ 1);          // issue 4 GLL for next tile
    asm volatile("s_waitcnt lgkmcnt(0)" ::: "memory");
    SBAR;                        // pin: no MFMA above this point
    __builtin_amdgcn_s_setprio(1);
    MFMA8;
    __builtin_amdgcn_s_setprio(0);
    SBAR;                        // pin: drain stays after MFMA
    asm volatile("s_waitcnt vmcnt(0)" ::: "memory");  // kt+1 landed (shadowed)
    __builtin_amdgcn_s_barrier();
  }
  // tail tile 15 (buf 1): no staging, no trailing barrier needed
  RD_FRAGS(1);
  asm volatile("s_waitcnt lgkmcnt(0)" ::: "memory");
  SBAR;
  MFMA8;

  // ===== epilogue (32x32 C/D: col=l31, row=(r&3)+8*(r>>2)+4*l5) =====
  const float C = 1.4426950408889634f / T_TEMP;   // log2(e)/T
  float invc[2];
  int jc[2];
#pragma unroll
  for (int nt = 0; nt < 2; ++nt) {
    jc[nt] = gcol0 + wcol + nt * 32 + l31;
    invc[nt] = inv_n[jc[nt]] * C;
  }

  float cp[2] = {};
#pragma unroll
  for (int mt = 0; mt < 2; ++mt) {
    const int ibase = grow0 + wrow + mt * 32;
    float4 ir[4];
#pragma unroll
    for (int g = 0; g < 4; ++g)
      ir[g] = *(const float4*)&inv_n[ibase + g * 8 + 4 * l5];

    float rp[16];
#pragma unroll
    for (int r = 0; r < 16; ++r) {
      const int row = (r & 3) + 8 * (r >> 2) + 4 * l5;
      const int i = ibase + row;
      const float sc = ((const float*)&ir[r >> 2])[r & 3];
      float e0 = exp2f((float)acc[mt][0][r] * sc * invc[0]);
      float e1 = exp2f((float)acc[mt][1][r] * sc * invc[1]);
      if (jc[0] == i || jc[0] == i + N_ROWS) e0 = 0.0f;
      if (jc[1] == i || jc[1] == i + N_ROWS) e1 = 0.0f;
      rp[r] = e0 + e1;
      cp[0] += e0;
      cp[1] += e1;
    }
#pragma unroll
    for (int mk = 1; mk <= 16; mk <<= 1)
#pragma unroll
      for (int r = 0; r < 16; ++r)
        rp[r] += __shfl_xor(rp[r], mk, 32);
    if (l31 == 0) {
#pragma unroll
      for (int r = 0; r < 16; ++r)
        atomicAdd(&rowsum[ibase + (r & 3) + 8 * (r >> 2) + 4 * l5], rp[r]);
    }
  }

  if (sym) {
#pragma unroll
    for (int nt = 0; nt < 2; ++nt) {
      float v = cp[nt];
      v += __shfl_xor(v, 32, 64);   // combine l5 halves (rows)
      if (l5 == 0)
        atomicAdd(&rowsum[jc[nt]], v);
    }
  }
#undef STG
#undef RD_FRAGS
#undef MFMA8
}

// Single block: cumsum(rowsum) -> sum(log(neg) - logpos) + sum(js) -> out[0]
__global__ __launch_bounds__(256) void final_kernel(
    const float* __restrict__ rowsum, const float* __restrict__ logpos,
    const float* __restrict__ js, float* __restrict__ out) {
  __shared__ float scan[256];
  __shared__ double ds[4];
  __shared__ float fs[4];
  const int tid = threadIdx.x;
  float loc[16];
  float run = 0.f, jl = 0.f;
#pragma unroll
  for (int k = 0; k < 16; ++k) {
    loc[k] = rowsum[tid * 16 + k];
    run += loc[k];
    jl += js[tid * 16 + k];
  }
  scan[tid] = run;
  __syncthreads();
  for (int d = 1; d < 256; d <<= 1) {
    float add = (tid >= d) ? scan[tid - d] : 0.0f;
    __syncthreads();
    scan[tid] += add;
    __syncthreads();
  }
  float c = scan[tid] - run;  // exclusive prefix
  double acc = 0.0;
#pragma unroll
  for (int k = 0; k < 16; ++k) {
    c += loc[k];
    acc += (double)(logf(c) - logpos[tid * 16 + k]);
  }
#pragma unroll
  for (int m = 32; m >= 1; m >>= 1) {
    acc += __shfl_xor(acc, m, 64);
    jl  += __shfl_xor(jl, m, 64);
  }
  if ((tid & 63) == 0) { ds[tid >> 6] = acc; fs[tid >> 6] = jl; }
  __syncthreads();
  if (tid == 0) {
    const double nce = ds[0] + ds[1] + ds[2] + ds[3];
    const double jst = (double)(fs[0] + fs[1] + fs[2] + fs[3]);
    out[0] = (float)(nce + jst / (2.0 * N_ROWS));
  }
}

extern "C" void kernel_launch(void* const* d_in, const int* in_sizes, int n_in,
                              void* d_out, int out_size, void* d_ws, size_t ws_size,
                              hipStream_t stream) {
  const float* x = (const float*)d_in[0];
  const float* y = (const float*)d_in[1];
  float* out = (float*)d_out;

  char* ws = (char*)d_ws;
  unsigned char* Bb = (unsigned char*)ws;                  // [8192][1024] i8, 8 MB
  float* inv_n  = (float*)(ws + (size_t)8 * 1024 * 1024);  // 8192
  float* logpos = inv_n + 8192;                            // 4096
  float* rowsum = logpos + 4096;                           // 4096
  float* js     = rowsum + 4096;                           // 4096

  prep_kernel<<<N_ROWS / 4, 256, 0, stream>>>(x, y, Bb, inv_n, logpos, js, rowsum);
  gemm_fused<<<1552, 256, 0, stream>>>(Bb, inv_n, rowsum);
  final_kernel<<<1, 256, 0, stream>>>(rowsum, logpos, js, out);
}

// Round 18
// 67.724 us; speedup vs baseline: 1.3960x; 1.3960x over previous
//
#include <hip/hip_runtime.h>
#include <stdint.h>

#define N_ROWS 4096
#define D_DIM  1024
#define ROWB   1024   // bytes per row in i8
#define T_TEMP 0.15f

#define AS1 __attribute__((address_space(1)))
#define AS3 __attribute__((address_space(3)))

typedef int i32x4v __attribute__((ext_vector_type(4)));

__device__ __forceinline__ float wsum(float v) {
#pragma unroll
  for (int m = 32; m >= 1; m >>= 1) v += __shfl_xor(v, m, 64);
  return v;
}
__device__ __forceinline__ float wmax(float v) {
#pragma unroll
  for (int m = 32; m >= 1; m >>= 1) v = fmaxf(v, __shfl_xor(v, m, 64));
  return v;
}

// One WAVE per row (no barriers): norms, x.y dot (-> log pos), softmax-JS
// per-row term -> js[row]. Per-row symmetric i8 quantization (scale
// cancels in cosine): q = rint(x * 127/rowmax|x|), natural row-major
// layout in Bb = [x;y]; inv_n = 1/|q|. Zeroes rowsum. (R15-verified.)
__global__ __launch_bounds__(256) void prep_kernel(
    const float* __restrict__ x, const float* __restrict__ y,
    unsigned char* __restrict__ Bb, float* __restrict__ inv_n,
    float* __restrict__ logpos, float* __restrict__ js,
    float* __restrict__ rowsum) {
  if (threadIdx.x < 4) rowsum[blockIdx.x * 4 + threadIdx.x] = 0.0f;

  const int wid = threadIdx.x >> 6, lane = threadIdx.x & 63;
  const int row = blockIdx.x * 4 + wid;
  const float4* xp = (const float4*)(x + (size_t)row * D_DIM) + lane * 4;
  const float4* yp = (const float4*)(y + (size_t)row * D_DIM) + lane * 4;

  float xv[16], yv[16];
#pragma unroll
  for (int i = 0; i < 4; ++i) {
    float4 a = xp[i], b = yp[i];
    xv[i*4+0]=a.x; xv[i*4+1]=a.y; xv[i*4+2]=a.z; xv[i*4+3]=a.w;
    yv[i*4+0]=b.x; yv[i*4+1]=b.y; yv[i*4+2]=b.z; yv[i*4+3]=b.w;
  }

  float sx2=0.f, sy2=0.f, sxy=0.f, mx=-1e30f, my=-1e30f, ax=0.f, ay=0.f;
#pragma unroll
  for (int k = 0; k < 16; ++k) {
    sx2 = fmaf(xv[k], xv[k], sx2);
    sy2 = fmaf(yv[k], yv[k], sy2);
    sxy = fmaf(xv[k], yv[k], sxy);
    mx = fmaxf(mx, xv[k]); my = fmaxf(my, yv[k]);
    ax = fmaxf(ax, fabsf(xv[k])); ay = fmaxf(ay, fabsf(yv[k]));
  }
  sx2 = wsum(sx2); sy2 = wsum(sy2); sxy = wsum(sxy);
  mx = wmax(mx);  my = wmax(my);
  ax = wmax(ax);  ay = wmax(ay);

  float ex[16], ey[16], sex=0.f, sey=0.f;
#pragma unroll
  for (int k = 0; k < 16; ++k) {
    ex[k] = __expf(xv[k] - mx); ey[k] = __expf(yv[k] - my);
    sex += ex[k]; sey += ey[k];
  }
  sex = wsum(sex); sey = wsum(sey);
  const float lsex = __logf(sex), lsey = __logf(sey);
  const float rsex = 1.f / sex,  rsey = 1.f / sey;

  float term = 0.f;
#pragma unroll
  for (int k = 0; k < 16; ++k) {
    float a = ex[k] * rsex, b = ey[k] * rsey;
    float lm = __logf(0.5f * (a + b));
    term += a * ((xv[k] - mx - lsex) - lm) + b * ((yv[k] - my - lsey) - lm);
  }
  term = wsum(term);

  // quantize: q = rint(x * 127/rowmax); accumulate |q|^2
  const float sxq = 127.0f / ax, syq = 127.0f / ay;
  int qx[16], qy[16];
  float q2x = 0.f, q2y = 0.f;
#pragma unroll
  for (int k = 0; k < 16; ++k) {
    qx[k] = (int)rintf(xv[k] * sxq);
    qy[k] = (int)rintf(yv[k] * syq);
    q2x += (float)(qx[k] * qx[k]);
    q2y += (float)(qy[k] * qy[k]);
  }
  q2x = wsum(q2x); q2y = wsum(q2y);

  if (lane == 0) {
    const float nx = sqrtf(sx2), ny = sqrtf(sy2);
    inv_n[row] = rsqrtf(q2x);            // 1/|q_x|
    inv_n[N_ROWS + row] = rsqrtf(q2y);   // 1/|q_y|
    logpos[row] = sxy / fmaxf(nx * ny, 1e-8f) / T_TEMP;  // ln(pos), exact fp32
    js[row] = term;
  }

  int p[4], q[4];
#pragma unroll
  for (int w = 0; w < 4; ++w) {
    p[w] = (qx[4*w] & 255) | ((qx[4*w+1] & 255) << 8) |
           ((qx[4*w+2] & 255) << 16) | ((qx[4*w+3] & 255) << 24);
    q[w] = (qy[4*w] & 255) | ((qy[4*w+1] & 255) << 8) |
           ((qy[4*w+2] & 255) << 16) | ((qy[4*w+3] & 255) << 24);
  }
  *(int4*)(Bb + (size_t)row * ROWB + lane * 16) = make_int4(p[0], p[1], p[2], p[3]);
  *(int4*)(Bb + (size_t)(N_ROWS + row) * ROWB + lane * 16) = make_int4(q[0], q[1], q[2], q[3]);
}

// ===== i8 symmetric fused GEMM, 128x128, 4 waves, BK=64, raw 2-phase =====
// R15's winning schedule (best measured: gemm 47.1us, conflicts 0,
// absmax 0) with ONE reorder: the 4 staging GLLs issue BEFORE the 8
// ds_reads each tile, gaining ~100-150cyc extra latency shadow ahead of
// the vmcnt(0) drain. Waits/barrier/ledger identical to R15 (buf b^1's
// prior reads completed at tile kt-1's lgkmcnt(0) before the preceding
// barrier, so staging into it first is the same WAR proof).
#define GLL(src, dst) __builtin_amdgcn_global_load_lds((const AS1 void*)(src), (AS3 void*)(dst), 16, 0, 0)
#define SBAR __builtin_amdgcn_sched_barrier(0)

__global__ __launch_bounds__(256, 3) void gemm_fused(
    const unsigned char* __restrict__ Bb, const float* __restrict__ inv_n,
    float* __restrict__ rowsum) {
  __shared__ __align__(16) char As[2 * 8192];   // [buf][128][64]
  __shared__ __align__(16) char Bs[2 * 8192];
  const int tid = threadIdx.x;
  const int wid = tid >> 6, lane = tid & 63;
  const int lo = lane & 15, hi = lane >> 4;

  int bi, bj;
  bool sym = false;
  {
    const int idx = blockIdx.x;
    if (idx < 1024) {
      bi = idx >> 5; bj = 32 + (idx & 31);
    } else {
      const int t = idx - 1024;
      int b = (int)((65.0 - sqrt((double)(4225 - 8 * t))) * 0.5);
      while ((b + 1) * (65 - (b + 1)) / 2 <= t) ++b;
      while (b * (65 - b) / 2 > t) --b;
      bi = b;
      bj = b + (t - b * (65 - b) / 2);
      sym = (bi != bj);
    }
  }
  const int grow0 = bi * 128;
  const int gcol0 = bj * 128;
  const int wrow = (wid >> 1) * 64, wcol = (wid & 1) * 64;

  i32x4v acc[4][4] = {};

  // staging: thread t -> row sr = t>>2 (per 64-row half), slot t&3;
  // source 16B unit pre-swizzled h = (t&3) ^ ((t>>3)&3) (== (row>>1)&3).
  const int sr = tid >> 2;
  const int sh = (tid & 3) ^ ((tid >> 3) & 3);
  const char* gA = (const char*)Bb + (size_t)(grow0 + sr) * ROWB + sh * 16;
  const char* gB = (const char*)Bb + (size_t)(gcol0 + sr) * ROWB + sh * 16;

#define STG(kt_, b_) do { \
    GLL(gA + (size_t)(kt_) * 64,                      As + (b_) * 8192 + tid * 16); \
    GLL(gA + 64 * (size_t)ROWB + (size_t)(kt_) * 64,  As + (b_) * 8192 + 4096 + tid * 16); \
    GLL(gB + (size_t)(kt_) * 64,                      Bs + (b_) * 8192 + tid * 16); \
    GLL(gB + 64 * (size_t)ROWB + (size_t)(kt_) * 64,  Bs + (b_) * 8192 + 4096 + tid * 16); \
  } while (0)

  // fragment read: row = base + lo, slot = hi ^ xr (zero-conflict pattern);
  // delivered bytes = natural k-unit hi (k = hi*16..hi*16+15) for all rows.
  const int xr = (lo >> 1) & 3;
  const int rslot = (hi ^ xr) * 16;

  i32x4v a[4], bv[4];

#define RD_FRAGS(b_) do { _Pragma("unroll") \
    for (int m = 0; m < 4; ++m) \
      a[m] = *(const i32x4v*)(As + (b_) * 8192 + (wrow + m * 16 + lo) * 64 + rslot); \
    _Pragma("unroll") \
    for (int n = 0; n < 4; ++n) \
      bv[n] = *(const i32x4v*)(Bs + (b_) * 8192 + (wcol + n * 16 + lo) * 64 + rslot); \
  } while (0)

#define MFMA16 do { _Pragma("unroll") \
    for (int n = 0; n < 4; ++n) \
      _Pragma("unroll") \
      for (int m = 0; m < 4; ++m) \
        acc[m][n] = __builtin_amdgcn_mfma_i32_16x16x64_i8( \
            a[m], bv[n], acc[m][n], 0, 0, 0); \
  } while (0)

  // prologue: stage tile 0 into buf 0, publish
  STG(0, 0);
  asm volatile("s_waitcnt vmcnt(0)" ::: "memory");
  __builtin_amdgcn_s_barrier();

#pragma unroll 1
  for (int kt = 0; kt < 15; ++kt) {
    const int b = kt & 1;
    STG(kt + 1, b ^ 1);          // issue 4 GLL for next tile FIRST (shadow++)
    SBAR;
    RD_FRAGS(b);                 // 8 ds_read_b128 from buf b
    asm volatile("s_waitcnt lgkmcnt(0)" ::: "memory");
    SBAR;                        // pin: no MFMA above this point
    __builtin_amdgcn_s_setprio(1);
    MFMA16;
    __builtin_amdgcn_s_setprio(0);
    SBAR;                        // pin: drain stays after MFMA
    asm volatile("s_waitcnt vmcnt(0)" ::: "memory");  // kt+1 landed (shadowed)
    __builtin_amdgcn_s_barrier();
  }
  // tail tile 15 (buf 1): no staging, no trailing barrier needed
  RD_FRAGS(1);
  asm volatile("s_waitcnt lgkmcnt(0)" ::: "memory");
  SBAR;
  MFMA16;

  // epilogue: scale -> exp2 -> mask diag -> row-reduce (+col-reduce if sym)
  const float C = 1.4426950408889634f / T_TEMP;   // log2(e)/T
  float invc[4], invr[4][4];
#pragma unroll
  for (int n = 0; n < 4; ++n)
    invc[n] = inv_n[gcol0 + wcol + n * 16 + lo] * C;
#pragma unroll
  for (int m = 0; m < 4; ++m)
#pragma unroll
    for (int r = 0; r < 4; ++r)
      invr[m][r] = inv_n[grow0 + wrow + m * 16 + hi * 4 + r];

  float rp[4][4] = {};
  float cp[4] = {};
#pragma unroll
  for (int m = 0; m < 4; ++m)
#pragma unroll
    for (int n = 0; n < 4; ++n)
#pragma unroll
      for (int r = 0; r < 4; ++r) {
        const int i = grow0 + wrow + m * 16 + hi * 4 + r;
        const int j = gcol0 + wcol + n * 16 + lo;
        float e2 = exp2f((float)acc[m][n][r] * invr[m][r] * invc[n]);
        if (j == i || j == i + N_ROWS) e2 = 0.0f;
        rp[m][r] += e2;
        cp[n] += e2;
      }

#pragma unroll
  for (int m = 0; m < 4; ++m)
#pragma unroll
    for (int r = 0; r < 4; ++r) {
      float v = rp[m][r];
      v += __shfl_xor(v, 1, 16);
      v += __shfl_xor(v, 2, 16);
      v += __shfl_xor(v, 4, 16);
      v += __shfl_xor(v, 8, 16);
      if (lo == 0)
        atomicAdd(&rowsum[grow0 + wrow + m * 16 + hi * 4 + r], v);
    }

  if (sym) {
#pragma unroll
    for (int n = 0; n < 4; ++n) {
      float v = cp[n];
      v += __shfl_xor(v, 16, 64);
      v += __shfl_xor(v, 32, 64);
      if (hi == 0)
        atomicAdd(&rowsum[gcol0 + wcol + n * 16 + lo], v);
    }
  }
#undef STG
#undef RD_FRAGS
#undef MFMA16
}

// Single block: cumsum(rowsum) -> sum(log(neg) - logpos) + sum(js) -> out[0]
__global__ __launch_bounds__(256) void final_kernel(
    const float* __restrict__ rowsum, const float* __restrict__ logpos,
    const float* __restrict__ js, float* __restrict__ out) {
  __shared__ float scan[256];
  __shared__ double ds[4];
  __shared__ float fs[4];
  const int tid = threadIdx.x;
  float loc[16];
  float run = 0.f, jl = 0.f;
#pragma unroll
  for (int k = 0; k < 16; ++k) {
    loc[k] = rowsum[tid * 16 + k];
    run += loc[k];
    jl += js[tid * 16 + k];
  }
  scan[tid] = run;
  __syncthreads();
  for (int d = 1; d < 256; d <<= 1) {
    float add = (tid >= d) ? scan[tid - d] : 0.0f;
    __syncthreads();
    scan[tid] += add;
    __syncthreads();
  }
  float c = scan[tid] - run;  // exclusive prefix
  double acc = 0.0;
#pragma unroll
  for (int k = 0; k < 16; ++k) {
    c += loc[k];
    acc += (double)(logf(c) - logpos[tid * 16 + k]);
  }
#pragma unroll
  for (int m = 32; m >= 1; m >>= 1) {
    acc += __shfl_xor(acc, m, 64);
    jl  += __shfl_xor(jl, m, 64);
  }
  if ((tid & 63) == 0) { ds[tid >> 6] = acc; fs[tid >> 6] = jl; }
  __syncthreads();
  if (tid == 0) {
    const double nce = ds[0] + ds[1] + ds[2] + ds[3];
    const double jst = (double)(fs[0] + fs[1] + fs[2] + fs[3]);
    out[0] = (float)(nce + jst / (2.0 * N_ROWS));
  }
}

extern "C" void kernel_launch(void* const* d_in, const int* in_sizes, int n_in,
                              void* d_out, int out_size, void* d_ws, size_t ws_size,
                              hipStream_t stream) {
  const float* x = (const float*)d_in[0];
  const float* y = (const float*)d_in[1];
  float* out = (float*)d_out;

  char* ws = (char*)d_ws;
  unsigned char* Bb = (unsigned char*)ws;                  // [8192][1024] i8, 8 MB
  float* inv_n  = (float*)(ws + (size_t)8 * 1024 * 1024);  // 8192
  float* logpos = inv_n + 8192;                            // 4096
  float* rowsum = logpos + 4096;                           // 4096
  float* js     = rowsum + 4096;                           // 4096

  prep_kernel<<<N_ROWS / 4, 256, 0, stream>>>(x, y, Bb, inv_n, logpos, js, rowsum);
  gemm_fused<<<1552, 256, 0, stream>>>(Bb, inv_n, rowsum);
  final_kernel<<<1, 256, 0, stream>>>(rowsum, logpos, js, out);
}

// Round 19
// 66.625 us; speedup vs baseline: 1.4190x; 1.0165x over previous
//
#include <hip/hip_runtime.h>
#include <stdint.h>

#define N_ROWS 4096
#define D_DIM  1024
#define ROWB   1024   // bytes per row in i8
#define T_TEMP 0.15f

#define AS1 __attribute__((address_space(1)))
#define AS3 __attribute__((address_space(3)))

typedef int i32x4v __attribute__((ext_vector_type(4)));

__device__ __forceinline__ float wsum(float v) {
#pragma unroll
  for (int m = 32; m >= 1; m >>= 1) v += __shfl_xor(v, m, 64);
  return v;
}
__device__ __forceinline__ float wmax(float v) {
#pragma unroll
  for (int m = 32; m >= 1; m >>= 1) v = fmaxf(v, __shfl_xor(v, m, 64));
  return v;
}

// One WAVE per row (no barriers). COALESCED loads: lane reads float4 at
// j = i*64 + lane (contiguous 1KB per instruction; R18's lane*4 layout
// spanned 64 cache lines/instr). The row-element permutation is shared by
// all rows and every consumer is an order-agnostic reduction, so semantics
// are unchanged. i8 stores re-indexed to match (4x coalesced dword).
__global__ __launch_bounds__(256) void prep_kernel(
    const float* __restrict__ x, const float* __restrict__ y,
    unsigned char* __restrict__ Bb, float* __restrict__ inv_n,
    float* __restrict__ logpos, float* __restrict__ js,
    float* __restrict__ rowsum) {
  if (threadIdx.x < 4) rowsum[blockIdx.x * 4 + threadIdx.x] = 0.0f;

  const int wid = threadIdx.x >> 6, lane = threadIdx.x & 63;
  const int row = blockIdx.x * 4 + wid;
  const float4* xp = (const float4*)(x + (size_t)row * D_DIM);
  const float4* yp = (const float4*)(y + (size_t)row * D_DIM);

  float xv[16], yv[16];
#pragma unroll
  for (int i = 0; i < 4; ++i) {
    float4 a = xp[i * 64 + lane], b = yp[i * 64 + lane];
    xv[i*4+0]=a.x; xv[i*4+1]=a.y; xv[i*4+2]=a.z; xv[i*4+3]=a.w;
    yv[i*4+0]=b.x; yv[i*4+1]=b.y; yv[i*4+2]=b.z; yv[i*4+3]=b.w;
  }

  float sx2=0.f, sy2=0.f, sxy=0.f, mx=-1e30f, my=-1e30f, ax=0.f, ay=0.f;
#pragma unroll
  for (int k = 0; k < 16; ++k) {
    sx2 = fmaf(xv[k], xv[k], sx2);
    sy2 = fmaf(yv[k], yv[k], sy2);
    sxy = fmaf(xv[k], yv[k], sxy);
    mx = fmaxf(mx, xv[k]); my = fmaxf(my, yv[k]);
    ax = fmaxf(ax, fabsf(xv[k])); ay = fmaxf(ay, fabsf(yv[k]));
  }
  sx2 = wsum(sx2); sy2 = wsum(sy2); sxy = wsum(sxy);
  mx = wmax(mx);  my = wmax(my);
  ax = wmax(ax);  ay = wmax(ay);

  float ex[16], ey[16], sex=0.f, sey=0.f;
#pragma unroll
  for (int k = 0; k < 16; ++k) {
    ex[k] = __expf(xv[k] - mx); ey[k] = __expf(yv[k] - my);
    sex += ex[k]; sey += ey[k];
  }
  sex = wsum(sex); sey = wsum(sey);
  const float lsex = __logf(sex), lsey = __logf(sey);
  const float rsex = 1.f / sex,  rsey = 1.f / sey;

  float term = 0.f;
#pragma unroll
  for (int k = 0; k < 16; ++k) {
    float a = ex[k] * rsex, b = ey[k] * rsey;
    float lm = __logf(0.5f * (a + b));
    term += a * ((xv[k] - mx - lsex) - lm) + b * ((yv[k] - my - lsey) - lm);
  }
  term = wsum(term);

  // quantize: q = rint(x * 127/rowmax); accumulate |q|^2
  const float sxq = 127.0f / ax, syq = 127.0f / ay;
  int qx[16], qy[16];
  float q2x = 0.f, q2y = 0.f;
#pragma unroll
  for (int k = 0; k < 16; ++k) {
    qx[k] = (int)rintf(xv[k] * sxq);
    qy[k] = (int)rintf(yv[k] * syq);
    q2x += (float)(qx[k] * qx[k]);
    q2y += (float)(qy[k] * qy[k]);
  }
  q2x = wsum(q2x); q2y = wsum(q2y);

  if (lane == 0) {
    const float nx = sqrtf(sx2), ny = sqrtf(sy2);
    inv_n[row] = rsqrtf(q2x);            // 1/|q_x|
    inv_n[N_ROWS + row] = rsqrtf(q2y);   // 1/|q_y|
    logpos[row] = sxy / fmaxf(nx * ny, 1e-8f) / T_TEMP;  // ln(pos), exact fp32
    js[row] = term;
  }

  int p[4], q[4];
#pragma unroll
  for (int w = 0; w < 4; ++w) {
    p[w] = (qx[4*w] & 255) | ((qx[4*w+1] & 255) << 8) |
           ((qx[4*w+2] & 255) << 16) | ((qx[4*w+3] & 255) << 24);
    q[w] = (qy[4*w] & 255) | ((qy[4*w+1] & 255) << 8) |
           ((qy[4*w+2] & 255) << 16) | ((qy[4*w+3] & 255) << 24);
  }
  int* ob = (int*)(Bb + (size_t)row * ROWB);
  int* oy = (int*)(Bb + (size_t)(N_ROWS + row) * ROWB);
#pragma unroll
  for (int w = 0; w < 4; ++w) {
    ob[w * 64 + lane] = p[w];   // element block w*64+lane (matches load perm)
    oy[w * 64 + lane] = q[w];
  }
}

// ===== i8 symmetric fused GEMM, 128x128, 4 waves, BK=64, raw 2-phase =====
// R15 byte-exact (best measured: gemm 47.1us, conflicts 0, absmax 0).
// Per tile: {8 ds_read from buf b | issue 4 GLL of kt+1 into b^1 |
// lgkmcnt(0) | 16 MFMA (mfma_i32_16x16x64_i8) | vmcnt(0) | s_barrier}.
#define GLL(src, dst) __builtin_amdgcn_global_load_lds((const AS1 void*)(src), (AS3 void*)(dst), 16, 0, 0)
#define SBAR __builtin_amdgcn_sched_barrier(0)

__global__ __launch_bounds__(256, 3) void gemm_fused(
    const unsigned char* __restrict__ Bb, const float* __restrict__ inv_n,
    float* __restrict__ rowsum) {
  __shared__ __align__(16) char As[2 * 8192];   // [buf][128][64]
  __shared__ __align__(16) char Bs[2 * 8192];
  const int tid = threadIdx.x;
  const int wid = tid >> 6, lane = tid & 63;
  const int lo = lane & 15, hi = lane >> 4;

  int bi, bj;
  bool sym = false;
  {
    const int idx = blockIdx.x;
    if (idx < 1024) {
      bi = idx >> 5; bj = 32 + (idx & 31);
    } else {
      const int t = idx - 1024;
      int b = (int)((65.0 - sqrt((double)(4225 - 8 * t))) * 0.5);
      while ((b + 1) * (65 - (b + 1)) / 2 <= t) ++b;
      while (b * (65 - b) / 2 > t) --b;
      bi = b;
      bj = b + (t - b * (65 - b) / 2);
      sym = (bi != bj);
    }
  }
  const int grow0 = bi * 128;
  const int gcol0 = bj * 128;
  const int wrow = (wid >> 1) * 64, wcol = (wid & 1) * 64;

  i32x4v acc[4][4] = {};

  // staging: thread t -> row sr = t>>2 (per 64-row half), slot t&3;
  // source 16B unit pre-swizzled h = (t&3) ^ ((t>>3)&3) (== (row>>1)&3).
  const int sr = tid >> 2;
  const int sh = (tid & 3) ^ ((tid >> 3) & 3);
  const char* gA = (const char*)Bb + (size_t)(grow0 + sr) * ROWB + sh * 16;
  const char* gB = (const char*)Bb + (size_t)(gcol0 + sr) * ROWB + sh * 16;

#define STG(kt_, b_) do { \
    GLL(gA + (size_t)(kt_) * 64,                      As + (b_) * 8192 + tid * 16); \
    GLL(gA + 64 * (size_t)ROWB + (size_t)(kt_) * 64,  As + (b_) * 8192 + 4096 + tid * 16); \
    GLL(gB + (size_t)(kt_) * 64,                      Bs + (b_) * 8192 + tid * 16); \
    GLL(gB + 64 * (size_t)ROWB + (size_t)(kt_) * 64,  Bs + (b_) * 8192 + 4096 + tid * 16); \
  } while (0)

  // fragment read: row = base + lo, slot = hi ^ xr (zero-conflict pattern)
  const int xr = (lo >> 1) & 3;
  const int rslot = (hi ^ xr) * 16;

  i32x4v a[4], bv[4];

#define RD_FRAGS(b_) do { _Pragma("unroll") \
    for (int m = 0; m < 4; ++m) \
      a[m] = *(const i32x4v*)(As + (b_) * 8192 + (wrow + m * 16 + lo) * 64 + rslot); \
    _Pragma("unroll") \
    for (int n = 0; n < 4; ++n) \
      bv[n] = *(const i32x4v*)(Bs + (b_) * 8192 + (wcol + n * 16 + lo) * 64 + rslot); \
  } while (0)

#define MFMA16 do { _Pragma("unroll") \
    for (int n = 0; n < 4; ++n) \
      _Pragma("unroll") \
      for (int m = 0; m < 4; ++m) \
        acc[m][n] = __builtin_amdgcn_mfma_i32_16x16x64_i8( \
            a[m], bv[n], acc[m][n], 0, 0, 0); \
  } while (0)

  // prologue: stage tile 0 into buf 0, publish
  STG(0, 0);
  asm volatile("s_waitcnt vmcnt(0)" ::: "memory");
  __builtin_amdgcn_s_barrier();

#pragma unroll 1
  for (int kt = 0; kt < 15; ++kt) {
    const int b = kt & 1;
    RD_FRAGS(b);                 // 8 ds_read_b128 from buf b
    SBAR;
    STG(kt + 1, b ^ 1);          // issue 4 GLL for next tile
    asm volatile("s_waitcnt lgkmcnt(0)" ::: "memory");
    SBAR;                        // pin: no MFMA above this point
    __builtin_amdgcn_s_setprio(1);
    MFMA16;
    __builtin_amdgcn_s_setprio(0);
    SBAR;                        // pin: drain stays after MFMA
    asm volatile("s_waitcnt vmcnt(0)" ::: "memory");  // kt+1 landed (shadowed)
    __builtin_amdgcn_s_barrier();
  }
  // tail tile 15 (buf 1): no staging, no trailing barrier needed
  RD_FRAGS(1);
  asm volatile("s_waitcnt lgkmcnt(0)" ::: "memory");
  SBAR;
  MFMA16;

  // epilogue: scale -> exp2 -> mask diag -> row-reduce (+col-reduce if sym)
  const float C = 1.4426950408889634f / T_TEMP;   // log2(e)/T
  float invc[4], invr[4][4];
#pragma unroll
  for (int n = 0; n < 4; ++n)
    invc[n] = inv_n[gcol0 + wcol + n * 16 + lo] * C;
#pragma unroll
  for (int m = 0; m < 4; ++m)
#pragma unroll
    for (int r = 0; r < 4; ++r)
      invr[m][r] = inv_n[grow0 + wrow + m * 16 + hi * 4 + r];

  float rp[4][4] = {};
  float cp[4] = {};
#pragma unroll
  for (int m = 0; m < 4; ++m)
#pragma unroll
    for (int n = 0; n < 4; ++n)
#pragma unroll
      for (int r = 0; r < 4; ++r) {
        const int i = grow0 + wrow + m * 16 + hi * 4 + r;
        const int j = gcol0 + wcol + n * 16 + lo;
        float e2 = exp2f((float)acc[m][n][r] * invr[m][r] * invc[n]);
        if (j == i || j == i + N_ROWS) e2 = 0.0f;
        rp[m][r] += e2;
        cp[n] += e2;
      }

#pragma unroll
  for (int m = 0; m < 4; ++m)
#pragma unroll
    for (int r = 0; r < 4; ++r) {
      float v = rp[m][r];
      v += __shfl_xor(v, 1, 16);
      v += __shfl_xor(v, 2, 16);
      v += __shfl_xor(v, 4, 16);
      v += __shfl_xor(v, 8, 16);
      if (lo == 0)
        atomicAdd(&rowsum[grow0 + wrow + m * 16 + hi * 4 + r], v);
    }

  if (sym) {
#pragma unroll
    for (int n = 0; n < 4; ++n) {
      float v = cp[n];
      v += __shfl_xor(v, 16, 64);
      v += __shfl_xor(v, 32, 64);
      if (hi == 0)
        atomicAdd(&rowsum[gcol0 + wcol + n * 16 + lo], v);
    }
  }
#undef STG
#undef RD_FRAGS
#undef MFMA16
}

// Single block, 1024 threads (was 256): cumsum(rowsum) ->
// sum(log(neg) - logpos) + sum(js) -> out[0]. 4 logf/thread instead of 16.
__global__ __launch_bounds__(1024) void final_kernel(
    const float* __restrict__ rowsum, const float* __restrict__ logpos,
    const float* __restrict__ js, float* __restrict__ out) {
  __shared__ float scan[1024];
  __shared__ double ds[16];
  __shared__ float fs[16];
  const int tid = threadIdx.x;
  float loc[4];
  float run = 0.f, jl = 0.f;
#pragma unroll
  for (int k = 0; k < 4; ++k) {
    loc[k] = rowsum[tid * 4 + k];
    run += loc[k];
    jl += js[tid * 4 + k];
  }
  scan[tid] = run;
  __syncthreads();
  for (int d = 1; d < 1024; d <<= 1) {
    float add = (tid >= d) ? scan[tid - d] : 0.0f;
    __syncthreads();
    scan[tid] += add;
    __syncthreads();
  }
  float c = scan[tid] - run;  // exclusive prefix
  double acc = 0.0;
#pragma unroll
  for (int k = 0; k < 4; ++k) {
    c += loc[k];
    acc += (double)(logf(c) - logpos[tid * 4 + k]);
  }
#pragma unroll
  for (int m = 32; m >= 1; m >>= 1) {
    acc += __shfl_xor(acc, m, 64);
    jl  += __shfl_xor(jl, m, 64);
  }
  if ((tid & 63) == 0) { ds[tid >> 6] = acc; fs[tid >> 6] = jl; }
  __syncthreads();
  if (tid == 0) {
    double nce = 0.0, jst = 0.0;
#pragma unroll
    for (int w = 0; w < 16; ++w) { nce += ds[w]; jst += (double)fs[w]; }
    out[0] = (float)(nce + jst / (2.0 * N_ROWS));
  }
}

extern "C" void kernel_launch(void* const* d_in, const int* in_sizes, int n_in,
                              void* d_out, int out_size, void* d_ws, size_t ws_size,
                              hipStream_t stream) {
  const float* x = (const float*)d_in[0];
  const float* y = (const float*)d_in[1];
  float* out = (float*)d_out;

  char* ws = (char*)d_ws;
  unsigned char* Bb = (unsigned char*)ws;                  // [8192][1024] i8, 8 MB
  float* inv_n  = (float*)(ws + (size_t)8 * 1024 * 1024);  // 8192
  float* logpos = inv_n + 8192;                            // 4096
  float* rowsum = logpos + 4096;                           // 4096
  float* js     = rowsum + 4096;                           // 4096

  prep_kernel<<<N_ROWS / 4, 256, 0, stream>>>(x, y, Bb, inv_n, logpos, js, rowsum);
  gemm_fused<<<1552, 256, 0, stream>>>(Bb, inv_n, rowsum);
  final_kernel<<<1, 1024, 0, stream>>>(rowsum, logpos, js, out);
}